// Round 1
// baseline (484.057 us; speedup 1.0000x reference)
//
#include <hip/hip_runtime.h>

#define VOCABN 100
#define EMBN 10
#define UNITSN 32
#define DENSEN 25
#define BATCHN 4096
#define SEQN 512
#define G3 96  // 3*UNITS

// sigmoid(x) = 1/(1+e^-x);  e^-x = 2^(-x*log2 e)
__device__ __forceinline__ float fast_sigmoid(float x) {
    float e = __builtin_amdgcn_exp2f(x * -1.4426950408889634f);
    return __builtin_amdgcn_rcpf(1.0f + e);
}
// tanh(x) = 2*sigmoid(2x) - 1
__device__ __forceinline__ float fast_tanh(float x) {
    float e = __builtin_amdgcn_exp2f(x * -2.8853900817779268f);
    float s = __builtin_amdgcn_rcpf(1.0f + e);
    return 2.0f * s - 1.0f;
}

// Mapping: 256 threads = 4 waves = 8 batch rows (half-wave per batch).
// lane j in [0,32) owns unit j: computes gate triple (z,r,h) for that unit,
// plus dense output column j (j<25). Recurrent + dense weights live in
// per-lane register columns; h is replicated 32-wide per lane, refreshed
// each step via LDS broadcast (ds_read_b128 x8).
__global__ __launch_bounds__(256, 2) void gru_fused_kernel(
    const int* __restrict__ inputs,
    const float* __restrict__ emb,
    const float* __restrict__ kern,
    const float* __restrict__ reck,
    const float* __restrict__ bias,
    const float* __restrict__ dw,
    const float* __restrict__ dbias,
    float* __restrict__ out)
{
    __shared__ float embP[VOCABN * G3];   // projected embedding + input bias, 38.4 KB
    __shared__ float hbuf[8][UNITSN];     // per-batch-row hidden state broadcast buffer
    __shared__ int   idxb[8][32];         // staged token indices

    const int tid = threadIdx.x;

    // Precompute embP[v][n] = bias[0][n] + sum_k emb[v,k]*kernel[k,n]
    for (int e = tid; e < VOCABN * G3; e += 256) {
        const int v = e / G3;
        const int n = e - v * G3;
        float a = bias[n];
        #pragma unroll
        for (int k = 0; k < EMBN; ++k)
            a = fmaf(emb[v * EMBN + k], kern[k * G3 + n], a);
        embP[e] = a;
    }
    __syncthreads();

    const int lane = tid & 63;
    const int wv   = tid >> 6;        // wave in block: 0..3
    const int g    = lane >> 5;       // half-wave: 0..1
    const int jj   = lane & 31;       // unit index
    const int row  = wv * 2 + g;      // local batch row: 0..7
    const int batch = blockIdx.x * 8 + row;

    // Per-lane weight columns (register-resident, constant-indexed only)
    float wz[UNITSN], wr[UNITSN], wh[UNITSN], wd[UNITSN];
    #pragma unroll
    for (int u = 0; u < UNITSN; ++u) {
        wz[u] = reck[u * G3 + jj];
        wr[u] = reck[u * G3 + 32 + jj];
        wh[u] = reck[u * G3 + 64 + jj];
    }
    #pragma unroll
    for (int u = 0; u < UNITSN; ++u)
        wd[u] = (jj < DENSEN) ? dw[u * DENSEN + jj] : 0.0f;

    const float rbz = bias[G3 + jj];
    const float rbr = bias[G3 + 32 + jj];
    const float rbh = bias[G3 + 64 + jj];
    const float dbj = (jj < DENSEN) ? dbias[jj] : 0.0f;

    const int* __restrict__ inrow  = inputs + (size_t)batch * SEQN;
    float* __restrict__     outrow = out + (size_t)batch * (size_t)(SEQN * DENSEN);

    float h[UNITSN];
    #pragma unroll
    for (int u = 0; u < UNITSN; ++u) h[u] = 0.0f;
    float hj = 0.0f;  // this lane's own unit value (avoids dynamic reg index)

    for (int t = 0; t < SEQN; ++t) {
        if ((t & 31) == 0) {
            // stage 32 indices per batch row; coalesced 128B per half-wave
            idxb[row][jj] = inrow[t + jj];
        }
        const int idx = idxb[row][t & 31];
        const float* ep = embP + idx * G3;
        const float xz = ep[jj];
        const float xr = ep[32 + jj];
        const float xh = ep[64 + jj];

        float rz = rbz, rr = rbr, rh = rbh;
        #pragma unroll
        for (int u = 0; u < UNITSN; ++u) {
            rz = fmaf(h[u], wz[u], rz);
            rr = fmaf(h[u], wr[u], rr);
            rh = fmaf(h[u], wh[u], rh);
        }

        const float z  = fast_sigmoid(xz + rz);
        const float r  = fast_sigmoid(xr + rr);
        const float hh = fast_tanh(fmaf(r, rh, xh));
        hj = fmaf(z, hj - hh, hh);  // z*h + (1-z)*hh

        // broadcast h_new to all lanes of the half-wave via LDS
        hbuf[row][jj] = hj;
        #pragma unroll
        for (int q = 0; q < 8; ++q) {
            const float4 v4 = *reinterpret_cast<const float4*>(&hbuf[row][q * 4]);
            h[q * 4 + 0] = v4.x;
            h[q * 4 + 1] = v4.y;
            h[q * 4 + 2] = v4.z;
            h[q * 4 + 3] = v4.w;
        }

        // fused dense + relu on h(t)
        float acc = dbj;
        #pragma unroll
        for (int u = 0; u < UNITSN; ++u)
            acc = fmaf(h[u], wd[u], acc);
        if (jj < DENSEN)
            outrow[t * DENSEN + jj] = fmaxf(acc, 0.0f);
    }
}

extern "C" void kernel_launch(void* const* d_in, const int* in_sizes, int n_in,
                              void* d_out, int out_size, void* d_ws, size_t ws_size,
                              hipStream_t stream) {
    const int*   inputs = (const int*)d_in[0];
    const float* emb    = (const float*)d_in[1];
    const float* kern   = (const float*)d_in[2];
    const float* reck   = (const float*)d_in[3];
    const float* bias   = (const float*)d_in[4];
    const float* dw     = (const float*)d_in[5];
    const float* dbias  = (const float*)d_in[6];
    float* out = (float*)d_out;

    dim3 grid(BATCHN / 8);
    dim3 block(256);
    hipLaunchKernelGGL(gru_fused_kernel, grid, block, 0, stream,
                       inputs, emb, kern, reck, bias, dw, dbias, out);
}